// Round 16
// baseline (726.536 us; speedup 1.0000x reference)
//
#include <hip/hip_runtime.h>
#include <math.h>

#define HWW 25600
#define CC 45
#define VV 724
#define PIXPB 8
#define NBLK 6400
#define TPB 256
#define NQ 9
#define E2 1e-6f

__device__ __forceinline__ float charb_(float x){ return sqrtf(fmaf(x,x,E2)); }

__device__ __forceinline__ float red64_(float v){
  #pragma unroll
  for (int o=32;o;o>>=1) v += __shfl_xor(v,o,64);
  return v;
}

__global__ __launch_bounds__(TPB)
void kmain(const float* __restrict__ pred, const float* __restrict__ tgt,
           const float* __restrict__ sf, const float* __restrict__ mask,
           float* __restrict__ ws)
{
  __shared__ float chP[CC], chT[CC], ps[VV], ts[VV];
  __shared__ float tv5s[5];
  __shared__ int   ti5s[5];
  __shared__ float stat[4];     // 0:mask 1:fodf 2:corr 3:power
  __shared__ float bnd[10];
  __shared__ float sRed[4][NQ];
  const int tid = threadIdx.x;
  float q[NQ];
  #pragma unroll
  for (int i=0;i<NQ;++i) q[i]=0.f;

  #pragma unroll 1
  for (int pp=0; pp<PIXPB; ++pp){
    const int pid = blockIdx.x*PIXPB + pp;
    const int b = pid / HWW, hw = pid - b*HWW;
    if (tid < CC){
      chP[tid] = pred[(size_t)(b*CC+tid)*HWW + hw];
      chT[tid] = tgt [(size_t)(b*CC+tid)*HWW + hw];
    }
    if (tid == 0) stat[0] = mask[pid];
    __syncthreads();

    // matvec: ps/ts = sf^T * ch
    #pragma unroll 1
    for (int v=tid; v<VV; v+=TPB){
      float ap=0.f, at=0.f;
      #pragma unroll 1
      for (int c=0;c<CC;++c){
        float s = sf[c*VV+v];
        ap = fmaf(s, chP[c], ap);
        at = fmaf(s, chT[c], at);
      }
      ps[v]=ap; ts[v]=at;
    }
    __syncthreads();

    // wave0: top-5 of relu(ts); thread 64 concurrently: serial channel stats
    if (tid < 64){
      float v5[5]={-1.f,-1.f,-1.f,-1.f,-1.f};
      int   i5[5]={0,0,0,0,0};
      #pragma unroll 1
      for (int v=tid; v<VV; v+=64){
        float x = fmaxf(ts[v],0.f);
        if (x > v5[4]){
          v5[4]=x; i5[4]=v;
          #pragma unroll
          for (int j=4;j>0;--j) if (v5[j]>v5[j-1]){
            float a=v5[j]; v5[j]=v5[j-1]; v5[j-1]=a;
            int   c=i5[j]; i5[j]=i5[j-1]; i5[j-1]=c;
          }
        }
      }
      #pragma unroll 1
      for (int o=32;o;o>>=1){
        float ov[5]; int oi[5];
        #pragma unroll
        for (int j=0;j<5;++j){ ov[j]=__shfl_xor(v5[j],o,64); oi[j]=__shfl_xor(i5[j],o,64); }
        #pragma unroll
        for (int j=0;j<5;++j){
          float x=ov[j]; int ix=oi[j];
          if (x > v5[4]){
            v5[4]=x; i5[4]=ix;
            #pragma unroll
            for (int k=4;k>0;--k) if (v5[k]>v5[k-1]){
              float a=v5[k]; v5[k]=v5[k-1]; v5[k-1]=a;
              int   c=i5[k]; i5[k]=i5[k-1]; i5[k-1]=c;
            }
          }
        }
      }
      if (tid == 0){
        #pragma unroll
        for (int j=0;j<5;++j){ tv5s[j]=v5[j]; ti5s[j]=i5[j]; }
      }
    } else if (tid == 64){
      float sp=0,st=0,spp=0,stt=0,spt=0,fod=0;
      #pragma unroll 1
      for (int i=0;i<10;++i) bnd[i]=0.f;
      #pragma unroll 1
      for (int c=0;c<CC;++c){
        float pv=chP[c], tv=chT[c];
        float p2=pv*pv, t2=tv*tv;
        sp+=pv; st+=tv; spp+=p2; stt+=t2; spt+=pv*tv;
        fod += charb_(pv-tv);
        int band = (c>=28)?4:(c>=15)?3:(c>=6)?2:(c>=1)?1:0;
        bnd[band]   += p2;
        bnd[band+5] += t2;
      }
      const float n = (float)CC;
      float mpm=sp/n, mtm=st/n;
      float cov = spt - n*mpm*mtm;
      float vp  = spp - n*mpm*mpm;
      float vt  = stt - n*mtm*mtm;
      float den = sqrtf(fmaxf(vp,0.f))*sqrtf(fmaxf(vt,0.f)) + 1e-6f;
      float pw = 0.f;
      #pragma unroll 1
      for (int i=0;i<5;++i) pw += charb_(sqrtf(bnd[i]+E2) - sqrtf(bnd[i+5]+E2));
      stat[1]=fod; stat[2]=1.f-cov/den; stat[3]=pw;
    }
    __syncthreads();

    const float mp = stat[0];
    if (tid == 0){
      q[0] += stat[1]*mp;
      q[1] += stat[2]*mp;
      q[7] += stat[3]*mp;
      q[8] += mp;
    }
    const float pk = fmaxf(tv5s[0], 1e-6f);
    const float invp = 1.f/pk;
    const float c2p = 4.f*invp*invp*mp;
    #pragma unroll 1
    for (int v=tid; v<VV; v+=TPB){
      float tsv=ts[v], psv=ps[v];
      float pos = fmaxf(tsv,0.f);
      float w = fmaf(c2p, pos*pos, mp);
      q[2] = fmaf(charb_(psv-tsv), w, q[2]);
      q[3] += w;
      q[4] += fmaxf(-psv,0.f)*mp;
    }
    if (tid < 5){
      float tv = tv5s[tid];
      if (tv > 0.25f*pk && mp > 0.5f){
        q[5] += charb_(ps[ti5s[tid]] - tv);
        q[6] += 1.f;
      }
    }
    __syncthreads();
  }

  #pragma unroll 1
  for (int i=0;i<NQ;++i) q[i] = red64_(q[i]);
  if ((tid & 63) == 0){
    #pragma unroll
    for (int i=0;i<NQ;++i) sRed[tid>>6][i] = q[i];
  }
  __syncthreads();
  if (tid < NQ)
    ws[blockIdx.x*16 + tid] = sRed[0][tid]+sRed[1][tid]+sRed[2][tid]+sRed[3][tid];
}

__global__ __launch_bounds__(TPB)
void kfinal(const float* __restrict__ ws, float* __restrict__ out)
{
  const int tid = threadIdx.x;
  float s[NQ];
  #pragma unroll
  for (int i=0;i<NQ;++i) s[i]=0.f;
  #pragma unroll 1
  for (int i=tid; i<NBLK; i+=TPB){
    #pragma unroll
    for (int k=0;k<NQ;++k) s[k] += ws[i*16+k];
  }
  #pragma unroll 1
  for (int i=0;i<NQ;++i) s[i] = red64_(s[i]);
  __shared__ float sw[4][NQ];
  if ((tid&63)==0){
    #pragma unroll
    for (int i=0;i<NQ;++i) sw[tid>>6][i]=s[i];
  }
  __syncthreads();
  if (tid==0){
    float t[NQ];
    #pragma unroll
    for (int i=0;i<NQ;++i) t[i]=sw[0][i]+sw[1][i]+sw[2][i]+sw[3][i];
    float msum = t[8];
    float fodf = t[0]/fmaxf(msum*45.f,1.f);
    float corr = t[1]/fmaxf(msum,1.f);
    float sfl  = t[2]/fmaxf(t[3],1.f);
    float nn   = t[4]/fmaxf(msum*724.f,1.f);
    float peak = t[5]/fmaxf(t[6],1.f);
    float pw   = t[7]/fmaxf(msum*5.f,1.f);
    out[0] = fodf + 0.1f*corr + sfl + 0.5f*peak + 0.1f*nn + 0.1f*pw;
  }
}

extern "C" void kernel_launch(void* const* d_in, const int* in_sizes, int n_in,
                              void* d_out, int out_size, void* d_ws, size_t ws_size,
                              hipStream_t stream) {
  kmain<<<NBLK, TPB, 0, stream>>>((const float*)d_in[0], (const float*)d_in[1],
                                  (const float*)d_in[2], (const float*)d_in[3],
                                  (float*)d_ws);
  kfinal<<<1, TPB, 0, stream>>>((const float*)d_ws, (float*)d_out);
}